// Round 11
// baseline (277.751 us; speedup 1.0000x reference)
//
#include <hip/hip_runtime.h>
#include <cstddef>
#include <cstdint>

#define NB 4
#define ND 512
#define NT 4096
#define NK 4096
#define NBT (NB * NT)
#define BKR 32         // real-k chunk
#define NCH (ND / BKR) // 16 chunks
#define CT (NK / 256)  // 16 candidate tiles

typedef __attribute__((ext_vector_type(4))) float f32x4;
typedef __attribute__((ext_vector_type(8))) short short8;
typedef __attribute__((ext_vector_type(8))) unsigned short u16x8;
typedef unsigned short u16;

__device__ inline u16 f2bf_rn(float f) {
  unsigned u = __float_as_uint(f);
  return (u16)((u + 0x7FFFu + ((u >> 16) & 1u)) >> 16);
}
__device__ inline float bf2f(u16 h) {
  return __uint_as_float(((unsigned)h) << 16);
}
__device__ inline void gload16(void* lds_p, const void* g) {
  __builtin_amdgcn_global_load_lds(
      (const __attribute__((address_space(1))) unsigned int*)g,
      (__attribute__((address_space(3))) unsigned int*)lds_p, 16, 0, 0);
}

// ---------------------------------------------------- e conversion + norm --
__global__ void conv_e_kernel(const float* __restrict__ emb,
                              u16* __restrict__ eh2, u16* __restrict__ el2,
                              float* __restrict__ enorm) {
  int row = blockIdx.x * 4 + (threadIdx.x >> 6);
  int l = threadIdx.x & 63;
  const float* e = emb + (size_t)row * ND;
  float s = 0.f;
#pragma unroll
  for (int i = 0; i < ND / 64; ++i) {
    int idx = l + i * 64;
    float v = e[idx];
    s += v * v;
    float v2 = 2.f * v;
    u16 h = f2bf_rn(v2);
    u16 lo = f2bf_rn(v2 - bf2f(h));
    eh2[(size_t)row * ND + idx] = h;
    el2[(size_t)row * ND + idx] = lo;
  }
#pragma unroll
  for (int m = 32; m; m >>= 1) s += __shfl_xor(s, m);
  if (l == 0) enorm[row] = s;
}

// ------------------- x conversion (+ transpose) + sum(x^2) partials --------
__global__ __launch_bounds__(256) void conv_x_kernel(const float* __restrict__ x,
                                                     u16* __restrict__ xh,
                                                     u16* __restrict__ xl,
                                                     float* __restrict__ xsq) {
  __shared__ float tile[64][68];
  const int tid = threadIdx.x;
  const int bt0 = blockIdx.x * 64, d0 = blockIdx.y * 64;
  const int b = bt0 / NT, t0 = bt0 % NT;
  const float* xb = x + (size_t)b * ND * NT;
  float s2 = 0.f;
  {
    const int tt4 = (tid & 15) * 4, ddb = tid >> 4;
#pragma unroll
    for (int p = 0; p < 4; ++p) {
      const int dd = ddb + p * 16;
      float4 v = *(const float4*)&xb[(size_t)(d0 + dd) * NT + t0 + tt4];
      s2 += v.x * v.x + v.y * v.y + v.z * v.z + v.w * v.w;
      *(float4*)&tile[dd][tt4] = v;
    }
  }
  __syncthreads();
  {
    const int t_loc = tid >> 2, dg = tid & 3;
    u16 hs[16], ls[16];
#pragma unroll
    for (int j = 0; j < 16; ++j) {
      float f = tile[dg * 16 + j][t_loc];
      u16 h = f2bf_rn(f);
      hs[j] = h;
      ls[j] = f2bf_rn(f - bf2f(h));
    }
    const size_t base = (size_t)(bt0 + t_loc) * ND + d0 + dg * 16;
    *(u16x8*)&xh[base] = *(const u16x8*)&hs[0];
    *(u16x8*)&xh[base + 8] = *(const u16x8*)&hs[8];
    *(u16x8*)&xl[base] = *(const u16x8*)&ls[0];
    *(u16x8*)&xl[base + 8] = *(const u16x8*)&ls[8];
  }
#pragma unroll
  for (int m = 32; m; m >>= 1) s2 += __shfl_xor(s2, m);
  __shared__ float wsum[4];
  if ((tid & 63) == 0) wsum[tid >> 6] = s2;
  __syncthreads();
  if (tid == 0)
    xsq[blockIdx.y * gridDim.x + blockIdx.x] =
        wsum[0] + wsum[1] + wsum[2] + wsum[3];
}

// ---------------------------------------------- 1-barrier GEMM + argmin ---
// Quad-operand residency, ONE barrier per chunk: within a chunk all ds_reads
// hit buffer `cur` and all stages write buffer `nb` -> no intra-chunk
// producer/consumer hazard; the only hazard is the buffer swap (end barrier).
// The whole chunk {8 stage issues, 24 ds_reads, 96 MFMA} is one straight-
// line region the compiler can fine-schedule (counted lgkmcnt interleave).
// vmcnt ledger: entry Q=[ops(t) 8]; stage ops(t+1) -> 16; VMC(8) drains
// ops(t); tail VMC(0). Prefetch slack = full chunk >> HBM latency.
// A-fragments are read per-qm (peak frag liveness 16 x short8 = 64 VGPR
// beside 128 AGPR acc -> ~230 of 256/wave budget; r9's spill avoided).
__device__ __forceinline__ void stage_op(
    u16 (&lds)[2][4][256][BKR], int bn, int op, int tn,
    const u16* __restrict__ src, int rowbase, int w, int l) {
  if (tn >= NCH) return;
  const int kA = tn * BKR;
#pragma unroll
  for (int i = 0; i < 2; ++i) {
    const int rowL = i * 128 + w * 16 + (l >> 2);
    const int gslot = (l & 3) ^ ((rowL >> 1) & 3);
    gload16(&lds[bn][op][i * 128 + w * 16][0],
            &src[(size_t)(rowbase + rowL) * ND + kA + gslot * 8]);
  }
}

__global__ __launch_bounds__(512, 2) void argmin_gemm_kernel(
    const u16* __restrict__ xh, const u16* __restrict__ xl,
    const u16* __restrict__ eh2, const u16* __restrict__ el2,
    const float* __restrict__ enorm, float* __restrict__ cand_v,
    int* __restrict__ cand_i) {
  __shared__ u16 lds[2][4][256][BKR];  // [buf][aH,aL,bH,bL][row][k] = 128 KiB
  const int tid = threadIdx.x;
  const int w = tid >> 6, l = tid & 63;
  const int l15 = l & 15, l4 = l >> 4;
  const int wm = w >> 2, wn = w & 3;
  // XCD-aware bijective swizzle: nwg=1024, 128 blocks per XCD chunk.
  const int id = blockIdx.x;
  const int id_sw = (id & 7) * 128 + (id >> 3);
  const int bx = id_sw & 63, by = id_sw >> 6;
  const int bt0 = bx * 256, c0g = by * 256;

  f32x4 acc[2][4][2][2];  // [qm][m][qn][n]
#pragma unroll
  for (int qm = 0; qm < 2; ++qm)
#pragma unroll
    for (int m = 0; m < 4; ++m)
#pragma unroll
      for (int qn = 0; qn < 2; ++qn)
#pragma unroll
        for (int n = 0; n < 2; ++n) acc[qm][m][qn][n] = (f32x4)0.f;

#define SLOT(row) (((l4) ^ (((row) >> 1) & 3)) * 8)
#define DS_A_Q(AF, OP, QM)                                               \
  _Pragma("unroll") for (int m = 0; m < 4; ++m) {                        \
    const int row = wm * 128 + (QM) * 64 + m * 16 + l15;                 \
    AF[m] = *(const short8*)&lds[cur][OP][row][SLOT(row)];               \
  }
#define DS_B(BF, OP)                                                     \
  _Pragma("unroll") for (int qn = 0; qn < 2; ++qn) {                     \
    _Pragma("unroll") for (int n = 0; n < 2; ++n) {                      \
      const int row = wn * 64 + qn * 32 + n * 16 + l15;                  \
      BF[qn * 2 + n] = *(const short8*)&lds[cur][OP][row][SLOT(row)];    \
    }                                                                    \
  }
#define MMQ(AF, BF, QM)                                                  \
  __builtin_amdgcn_s_setprio(1);                                         \
  _Pragma("unroll") for (int m = 0; m < 4; ++m) {                        \
    _Pragma("unroll") for (int qn = 0; qn < 2; ++qn) {                   \
      _Pragma("unroll") for (int n = 0; n < 2; ++n) {                    \
        acc[QM][m][qn][n] = __builtin_amdgcn_mfma_f32_16x16x32_bf16(     \
            AF[m], BF[qn * 2 + n], acc[QM][m][qn][n], 0, 0, 0);          \
      }                                                                  \
    }                                                                    \
  }                                                                      \
  __builtin_amdgcn_s_setprio(0);
#define BAR __builtin_amdgcn_s_barrier()
#define SB0 __builtin_amdgcn_sched_barrier(0)
#define VMC(N) asm volatile("s_waitcnt vmcnt(" #N ")" ::: "memory")

  // prologue: stage all 4 ops of chunk 0 into buf 0; drain; barrier.
  stage_op(lds, 0, 0, 0, xh, bt0, w, l);   // aH
  stage_op(lds, 0, 2, 0, eh2, c0g, w, l);  // bH
  stage_op(lds, 0, 3, 0, el2, c0g, w, l);  // bL
  stage_op(lds, 0, 1, 0, xl, bt0, w, l);   // aL
  VMC(0);
  BAR;
  SB0;

  for (int t = 0; t < NCH; ++t) {
    const int cur = t & 1;
    const int nb = cur ^ 1;
    const int tn = t + 1;
    // stage all 4 ops of chunk t+1 into nb (no-ops on the last chunk)
    stage_op(lds, nb, 0, tn, xh, bt0, w, l);
    stage_op(lds, nb, 2, tn, eh2, c0g, w, l);
    stage_op(lds, nb, 3, tn, el2, c0g, w, l);
    stage_op(lds, nb, 1, tn, xl, bt0, w, l);
    if (tn < NCH) {
      VMC(8);  // drain ops(t); ops(t+1) stay in flight a full chunk
    } else {
      VMC(0);
    }
    SB0;  // keep the reads below the wait
    short8 bH[4], bL[4];
    DS_B(bH, 2);
    DS_B(bL, 3);
#pragma unroll
    for (int qm = 0; qm < 2; ++qm) {
      short8 aHq[4], aLq[4];
      DS_A_Q(aHq, 0, qm);
      DS_A_Q(aLq, 1, qm);
      MMQ(aHq, bH, qm);
      MMQ(aHq, bL, qm);
      MMQ(aLq, bH, qm);
    }
    BAR;  // buffer swap: all waves done reading cur before it's restaged
    SB0;
  }
#undef SLOT
#undef DS_A_Q
#undef DS_B
#undef MMQ
#undef BAR
#undef SB0
#undef VMC

  // ---- epilogue: per-row argmin over this block's 256 cols ----
  __syncthreads();  // all loads drained (vmcnt 0 at exit); LDS reused below
  float* cvs = (float*)&lds[0][0][0][0];  // [4][256]
  int* cis = (int*)(cvs + 4 * 256);       // [4][256]

  float bv[2][4][4];
  int bi[2][4][4];
#pragma unroll
  for (int qm = 0; qm < 2; ++qm)
#pragma unroll
    for (int m = 0; m < 4; ++m)
#pragma unroll
      for (int q = 0; q < 4; ++q) {
        bv[qm][m][q] = INFINITY;
        bi[qm][m][q] = 0;
      }
#pragma unroll
  for (int qn = 0; qn < 2; ++qn)  // ascending col order -> first-min ties
#pragma unroll
    for (int n = 0; n < 2; ++n) {
      const int col = c0g + wn * 64 + qn * 32 + n * 16 + l15;
      const float en = enorm[col];
#pragma unroll
      for (int qm = 0; qm < 2; ++qm)
#pragma unroll
        for (int m = 0; m < 4; ++m)
#pragma unroll
          for (int q = 0; q < 4; ++q) {
            const float s = en - acc[qm][m][qn][n][q];
            if (s < bv[qm][m][q]) {
              bv[qm][m][q] = s;
              bi[qm][m][q] = col;
            }
          }
    }
#pragma unroll
  for (int msk = 1; msk < 16; msk <<= 1) {
#pragma unroll
    for (int qm = 0; qm < 2; ++qm)
#pragma unroll
      for (int m = 0; m < 4; ++m)
#pragma unroll
        for (int q = 0; q < 4; ++q) {
          const float ov = __shfl_xor(bv[qm][m][q], msk);
          const int oi = __shfl_xor(bi[qm][m][q], msk);
          if (ov < bv[qm][m][q] || (ov == bv[qm][m][q] && oi < bi[qm][m][q])) {
            bv[qm][m][q] = ov;
            bi[qm][m][q] = oi;
          }
        }
  }
  if (l15 == 0) {
#pragma unroll
    for (int qm = 0; qm < 2; ++qm)
#pragma unroll
      for (int m = 0; m < 4; ++m)
#pragma unroll
        for (int q = 0; q < 4; ++q) {
          const int row = wm * 128 + qm * 64 + m * 16 + l4 * 4 + q;
          cvs[wn * 256 + row] = bv[qm][m][q];
          cis[wn * 256 + row] = bi[qm][m][q];
        }
  }
  __syncthreads();
  if (tid < 256) {
    float v = cvs[tid];
    int bidx = cis[tid];
#pragma unroll
    for (int q = 1; q < 4; ++q) {  // ascending wn -> ascending cols
      const float ov = cvs[q * 256 + tid];
      const int oi = cis[q * 256 + tid];
      if (ov < v) {
        v = ov;
        bidx = oi;
      }
    }
    cand_v[(size_t)by * NBT + bt0 + tid] = v;
    cand_i[(size_t)by * NBT + bt0 + tid] = bidx;
  }
}

// -------- combine + exact fp32 top-2 rescore + loss partial (s_best) -------
__global__ __launch_bounds__(256) void combine_rescore_kernel(
    const float* __restrict__ cand_v, const int* __restrict__ cand_i,
    const float* __restrict__ x, const float* __restrict__ emb,
    const float* __restrict__ enorm, int* __restrict__ idx_ws,
    float* __restrict__ idxf, float* __restrict__ lpart) {
  const int r = blockIdx.x * 256 + threadIdx.x;
  float v1 = INFINITY, v2 = INFINITY;
  int i1 = 0, i2 = 0;
#pragma unroll
  for (int nt = 0; nt < CT; ++nt) {  // ascending nt -> ascending index
    const float v = cand_v[(size_t)nt * NBT + r];
    const int i = cand_i[(size_t)nt * NBT + r];
    if (v < v1) {
      v2 = v1;
      i2 = i1;
      v1 = v;
      i1 = i;
    } else if (v < v2) {
      v2 = v;
      i2 = i;
    }
  }
  const int b = r >> 12, t = r & (NT - 1);
  const float* xb = x + (size_t)b * ND * NT + t;
  const float* e1 = emb + (size_t)i1 * ND;
  const float* e2 = emb + (size_t)i2 * ND;
  float d1 = 0.f, d2 = 0.f;
#pragma unroll 8
  for (int d = 0; d < ND; ++d) {
    const float xv = xb[(size_t)d * NT];
    d1 += xv * e1[d];
    d2 += xv * e2[d];
  }
  const float s1 = enorm[i1] - 2.f * d1;
  const float s2 = enorm[i2] - 2.f * d2;
  const bool take2 = (s2 < s1 || (s2 == s1 && i2 < i1));
  const int best = take2 ? i2 : i1;
  idx_ws[r] = best;
  idxf[r] = (float)best;
  // per-row loss term: sum_d (x-v)^2 - sum_d x^2 = enorm[best] - 2*dot_best
  float lsum = take2 ? s2 : s1;
#pragma unroll
  for (int m = 32; m; m >>= 1) lsum += __shfl_xor(lsum, m);
  __shared__ float wsum[4];
  if ((threadIdx.x & 63) == 0) wsum[threadIdx.x >> 6] = lsum;
  __syncthreads();
  if (threadIdx.x == 0)
    lpart[blockIdx.x] = wsum[0] + wsum[1] + wsum[2] + wsum[3];
}

// ----------------------------------------------- gather (emb -> [B,D,T]) ---
__global__ __launch_bounds__(256) void gather_kernel(
    const float* __restrict__ emb, const int* __restrict__ idx_ws,
    float* __restrict__ vals_out) {
  __shared__ float tile[64][65];
  const int tid = threadIdx.x;
  const int bt0 = blockIdx.x * 64;
  const int d0 = blockIdx.y * 64;
  const int b = bt0 / NT;
  const int t0 = bt0 % NT;
  {
    const int dd4 = (tid & 15) * 4;
    const int ttb = tid >> 4;
#pragma unroll
    for (int p = 0; p < 4; ++p) {
      const int tt = ttb + p * 16;
      const int r = idx_ws[bt0 + tt];
      float4 v = *(const float4*)&emb[(size_t)r * ND + d0 + dd4];
      tile[tt][dd4 + 0] = v.x;
      tile[tt][dd4 + 1] = v.y;
      tile[tt][dd4 + 2] = v.z;
      tile[tt][dd4 + 3] = v.w;
    }
  }
  __syncthreads();
  {
    const int tt4 = (tid & 15) * 4;
    const int ddb = tid >> 4;
#pragma unroll
    for (int p = 0; p < 4; ++p) {
      const int dd = ddb + p * 16;
      float4 v;
      v.x = tile[tt4 + 0][dd];
      v.y = tile[tt4 + 1][dd];
      v.z = tile[tt4 + 2][dd];
      v.w = tile[tt4 + 3][dd];
      const size_t o = (size_t)b * ND * NT + (size_t)(d0 + dd) * NT + t0 + tt4;
      *(float4*)&vals_out[o] = v;
    }
  }
}

// ----------------------------------------------------------------- loss ----
__global__ void loss_kernel(const float* __restrict__ partials, int n,
                            float* __restrict__ out) {
  float s = 0.f;
  for (int i = threadIdx.x; i < n; i += 256) s += partials[i];
#pragma unroll
  for (int m = 32; m; m >>= 1) s += __shfl_xor(s, m);
  __shared__ float wsum[4];
  if ((threadIdx.x & 63) == 0) wsum[threadIdx.x >> 6] = s;
  __syncthreads();
  if (threadIdx.x == 0)
    out[0] = 2.0f * (wsum[0] + wsum[1] + wsum[2] + wsum[3]) /
             (float)((size_t)NB * ND * NT);
}

// --------------------------------------------------------------- launch ----
extern "C" void kernel_launch(void* const* d_in, const int* in_sizes, int n_in,
                              void* d_out, int out_size, void* d_ws,
                              size_t ws_size, hipStream_t stream) {
  const float* x = (const float*)d_in[0];
  const float* emb = (const float*)d_in[1];
  float* out = (float*)d_out;
  float* vals_out = out;                         // [B, D, T]
  float* idxf_out = out + (size_t)NB * ND * NT;  // [B, T] as float
  float* loss_out = idxf_out + NBT;              // scalar

  u16* xh = (u16*)d_ws;                            // NBT*ND
  u16* xl = xh + (size_t)NBT * ND;                 // NBT*ND
  u16* eh2 = xl + (size_t)NBT * ND;                // NK*ND
  u16* el2 = eh2 + (size_t)NK * ND;                // NK*ND
  float* enorm = (float*)(el2 + (size_t)NK * ND);  // NK
  float* cand_v = enorm + NK;                      // CT * NBT
  int* cand_i = (int*)(cand_v + (size_t)CT * NBT);
  int* idx_ws = cand_i + (size_t)CT * NBT;  // NBT
  float* partials = (float*)(idx_ws + NBT); // 2048 (x^2) + 64 (rescore)

  conv_e_kernel<<<NK / 4, 256, 0, stream>>>(emb, eh2, el2, enorm);
  conv_x_kernel<<<dim3(NBT / 64, ND / 64), 256, 0, stream>>>(x, xh, xl,
                                                             partials);
  argmin_gemm_kernel<<<1024, 512, 0, stream>>>(xh, xl, eh2, el2, enorm, cand_v,
                                               cand_i);
  combine_rescore_kernel<<<NBT / 256, 256, 0, stream>>>(
      cand_v, cand_i, x, emb, enorm, idx_ws, idxf_out, partials + 2048);
  gather_kernel<<<dim3(NBT / 64, ND / 64), 256, 0, stream>>>(emb, idx_ws,
                                                             vals_out);
  loss_kernel<<<1, 256, 0, stream>>>(partials, 2048 + 64, loss_out);
}

// Round 12
// 275.747 us; speedup vs baseline: 1.0073x; 1.0073x over previous
//
#include <hip/hip_runtime.h>
#include <cstddef>
#include <cstdint>

#define NB 4
#define ND 512
#define NT 4096
#define NK 4096
#define NBT (NB * NT)
#define BKR 32         // real-k chunk
#define NCH (ND / BKR) // 16 chunks
#define CT (NK / 256)  // 16 candidate tiles

typedef __attribute__((ext_vector_type(4))) float f32x4;
typedef __attribute__((ext_vector_type(8))) short short8;
typedef __attribute__((ext_vector_type(8))) unsigned short u16x8;
typedef unsigned short u16;

__device__ inline u16 f2bf_rn(float f) {
  unsigned u = __float_as_uint(f);
  return (u16)((u + 0x7FFFu + ((u >> 16) & 1u)) >> 16);
}
__device__ inline float bf2f(u16 h) {
  return __uint_as_float(((unsigned)h) << 16);
}
__device__ inline void gload16(void* lds_p, const void* g) {
  __builtin_amdgcn_global_load_lds(
      (const __attribute__((address_space(1))) unsigned int*)g,
      (__attribute__((address_space(3))) unsigned int*)lds_p, 16, 0, 0);
}

// ---------------------------------------------------- e conversion + norm --
__global__ void conv_e_kernel(const float* __restrict__ emb,
                              u16* __restrict__ eh2, u16* __restrict__ el2,
                              float* __restrict__ enorm) {
  int row = blockIdx.x * 4 + (threadIdx.x >> 6);
  int l = threadIdx.x & 63;
  const float* e = emb + (size_t)row * ND;
  float s = 0.f;
#pragma unroll
  for (int i = 0; i < ND / 64; ++i) {
    int idx = l + i * 64;
    float v = e[idx];
    s += v * v;
    float v2 = 2.f * v;
    u16 h = f2bf_rn(v2);
    u16 lo = f2bf_rn(v2 - bf2f(h));
    eh2[(size_t)row * ND + idx] = h;
    el2[(size_t)row * ND + idx] = lo;
  }
#pragma unroll
  for (int m = 32; m; m >>= 1) s += __shfl_xor(s, m);
  if (l == 0) enorm[row] = s;
}

// ------------------- x conversion (+ transpose) + sum(x^2) partials --------
__global__ __launch_bounds__(256) void conv_x_kernel(const float* __restrict__ x,
                                                     u16* __restrict__ xh,
                                                     u16* __restrict__ xl,
                                                     float* __restrict__ xsq) {
  __shared__ float tile[64][68];
  const int tid = threadIdx.x;
  const int bt0 = blockIdx.x * 64, d0 = blockIdx.y * 64;
  const int b = bt0 / NT, t0 = bt0 % NT;
  const float* xb = x + (size_t)b * ND * NT;
  float s2 = 0.f;
  {
    const int tt4 = (tid & 15) * 4, ddb = tid >> 4;
#pragma unroll
    for (int p = 0; p < 4; ++p) {
      const int dd = ddb + p * 16;
      float4 v = *(const float4*)&xb[(size_t)(d0 + dd) * NT + t0 + tt4];
      s2 += v.x * v.x + v.y * v.y + v.z * v.z + v.w * v.w;
      *(float4*)&tile[dd][tt4] = v;
    }
  }
  __syncthreads();
  {
    const int t_loc = tid >> 2, dg = tid & 3;
    u16 hs[16], ls[16];
#pragma unroll
    for (int j = 0; j < 16; ++j) {
      float f = tile[dg * 16 + j][t_loc];
      u16 h = f2bf_rn(f);
      hs[j] = h;
      ls[j] = f2bf_rn(f - bf2f(h));
    }
    const size_t base = (size_t)(bt0 + t_loc) * ND + d0 + dg * 16;
    *(u16x8*)&xh[base] = *(const u16x8*)&hs[0];
    *(u16x8*)&xh[base + 8] = *(const u16x8*)&hs[8];
    *(u16x8*)&xl[base] = *(const u16x8*)&ls[0];
    *(u16x8*)&xl[base + 8] = *(const u16x8*)&ls[8];
  }
#pragma unroll
  for (int m = 32; m; m >>= 1) s2 += __shfl_xor(s2, m);
  __shared__ float wsum[4];
  if ((tid & 63) == 0) wsum[tid >> 6] = s2;
  __syncthreads();
  if (tid == 0)
    xsq[blockIdx.y * gridDim.x + blockIdx.x] =
        wsum[0] + wsum[1] + wsum[2] + wsum[3];
}

// ---------------------------------------- 6-phase (m201-style) GEMM --------
// Quad-operand residency + m201-faithful fine phases: each phase =
// {reads(0-8 b128); stage(0-2 gload_lds); BAR; lgkmcnt(0); setprio(1);
//  16 MFMA; setprio(0); [counted VMC at P1/P5 only]; BAR}.
// Phases per chunk: P0 aH0*bH, P1 aH1*bH, P2 aH0*bL, P3 aH1*bL,
// P4 aL0*bH, P5 aL1*bH. vmcnt ledger: entry Q=[bL(t)2,aL(t)2];
// P0 stages aH+, P1 bH+ (Q=8) -> end-P1 VMC(4) drains bL,aL(t);
// P2 stages bL+, P4 aL+ (Q=8) -> end-P5 VMC(4) drains aH+,bH+ ->
// invariant. Last chunk: VMC(0) at both points. All stages target nb,
// all reads cur; swap hazard closed by the end-P5 barrier chain.
__device__ __forceinline__ void stage_op(
    u16 (&lds)[2][4][256][BKR], int bn, int op, int tn,
    const u16* __restrict__ src, int rowbase, int w, int l) {
  if (tn >= NCH) return;
  const int kA = tn * BKR;
#pragma unroll
  for (int i = 0; i < 2; ++i) {
    const int rowL = i * 128 + w * 16 + (l >> 2);
    const int gslot = (l & 3) ^ ((rowL >> 1) & 3);
    gload16(&lds[bn][op][i * 128 + w * 16][0],
            &src[(size_t)(rowbase + rowL) * ND + kA + gslot * 8]);
  }
}

__global__ __launch_bounds__(512, 2) void argmin_gemm_kernel(
    const u16* __restrict__ xh, const u16* __restrict__ xl,
    const u16* __restrict__ eh2, const u16* __restrict__ el2,
    const float* __restrict__ enorm, float* __restrict__ cand_v,
    int* __restrict__ cand_i) {
  __shared__ u16 lds[2][4][256][BKR];  // [buf][aH,aL,bH,bL][row][k] = 128 KiB
  const int tid = threadIdx.x;
  const int w = tid >> 6, l = tid & 63;
  const int l15 = l & 15, l4 = l >> 4;
  const int wm = w >> 2, wn = w & 3;
  // XCD-aware bijective swizzle: nwg=1024, 128 blocks per XCD chunk.
  const int id = blockIdx.x;
  const int id_sw = (id & 7) * 128 + (id >> 3);
  const int bx = id_sw & 63, by = id_sw >> 6;
  const int bt0 = bx * 256, c0g = by * 256;

  f32x4 acc[2][4][2][2];  // [qm][m][qn][n]
#pragma unroll
  for (int qm = 0; qm < 2; ++qm)
#pragma unroll
    for (int m = 0; m < 4; ++m)
#pragma unroll
      for (int qn = 0; qn < 2; ++qn)
#pragma unroll
        for (int n = 0; n < 2; ++n) acc[qm][m][qn][n] = (f32x4)0.f;

#define SLOT(row) (((l4) ^ (((row) >> 1) & 3)) * 8)
#define DS_A_Q(AF, OP, QM)                                               \
  _Pragma("unroll") for (int m = 0; m < 4; ++m) {                        \
    const int row = wm * 128 + (QM) * 64 + m * 16 + l15;                 \
    AF[m] = *(const short8*)&lds[cur][OP][row][SLOT(row)];               \
  }
#define DS_B(BF, OP)                                                     \
  _Pragma("unroll") for (int qn = 0; qn < 2; ++qn) {                     \
    _Pragma("unroll") for (int n = 0; n < 2; ++n) {                      \
      const int row = wn * 64 + qn * 32 + n * 16 + l15;                  \
      BF[qn * 2 + n] = *(const short8*)&lds[cur][OP][row][SLOT(row)];    \
    }                                                                    \
  }
#define MM16(AF, BF, QM)                                                 \
  __builtin_amdgcn_s_setprio(1);                                         \
  _Pragma("unroll") for (int m = 0; m < 4; ++m) {                        \
    _Pragma("unroll") for (int qn = 0; qn < 2; ++qn) {                   \
      _Pragma("unroll") for (int n = 0; n < 2; ++n) {                    \
        acc[QM][m][qn][n] = __builtin_amdgcn_mfma_f32_16x16x32_bf16(     \
            AF[m], BF[qn * 2 + n], acc[QM][m][qn][n], 0, 0, 0);          \
      }                                                                  \
    }                                                                    \
  }                                                                      \
  __builtin_amdgcn_s_setprio(0);
#define BAR __builtin_amdgcn_s_barrier()
#define LGK                                              \
  asm volatile("s_waitcnt lgkmcnt(0)" ::: "memory");     \
  __builtin_amdgcn_sched_barrier(0)
#define VMC(N) asm volatile("s_waitcnt vmcnt(" #N ")" ::: "memory")

  // prologue: stage chunk 0 (aH,bH,bL,aL); VMC(4) leaves [bL0,aL0] ->
  // entry invariant.
  stage_op(lds, 0, 0, 0, xh, bt0, w, l);   // aH
  stage_op(lds, 0, 2, 0, eh2, c0g, w, l);  // bH
  stage_op(lds, 0, 3, 0, el2, c0g, w, l);  // bL
  stage_op(lds, 0, 1, 0, xl, bt0, w, l);   // aL
  VMC(4);
  BAR;

  for (int t = 0; t < NCH; ++t) {
    const int cur = t & 1;
    const int nb = cur ^ 1;
    const int tn = t + 1;
    const bool nlast = (tn < NCH);
    short8 bH[4], bL[4], aH0[4], aH1[4], aL0[4], aL1[4];
    // ---- P0: reads bH, aH0; stage aH(t+1); MFMA aH0*bH -> acc[0] ----
    DS_B(bH, 2);
    DS_A_Q(aH0, 0, 0);
    stage_op(lds, nb, 0, tn, xh, bt0, w, l);
    BAR;
    LGK;
    MM16(aH0, bH, 0);
    BAR;
    // ---- P1: reads aH1; stage bH(t+1); MFMA aH1*bH -> acc[1] ----
    DS_A_Q(aH1, 0, 1);
    stage_op(lds, nb, 2, tn, eh2, c0g, w, l);
    BAR;
    LGK;
    MM16(aH1, bH, 1);
    if (nlast) {
      VMC(4);  // drain bL(t), aL(t); keep aH+,bH+ in flight
    } else {
      VMC(0);
    }
    BAR;
    // ---- P2: reads bL; stage bL(t+1); MFMA aH0*bL -> acc[0] ----
    DS_B(bL, 3);
    stage_op(lds, nb, 3, tn, el2, c0g, w, l);
    BAR;
    LGK;
    MM16(aH0, bL, 0);
    BAR;
    // ---- P3: reads aL0 (for P4); MFMA aH1*bL -> acc[1] ----
    DS_A_Q(aL0, 1, 0);
    BAR;
    LGK;
    MM16(aH1, bL, 1);
    BAR;
    // ---- P4: reads aL1 (for P5); stage aL(t+1); MFMA aL0*bH -> acc[0] ----
    DS_A_Q(aL1, 1, 1);
    stage_op(lds, nb, 1, tn, xl, bt0, w, l);
    BAR;
    LGK;
    MM16(aL0, bH, 0);
    BAR;
    // ---- P5: MFMA aL1*bH -> acc[1]; counted drain; swap barrier ----
    MM16(aL1, bH, 1);
    if (nlast) {
      VMC(4);  // drain aH(t+1), bH(t+1); keep bL+,aL+ -> invariant
    } else {
      VMC(0);
    }
    BAR;
  }
#undef SLOT
#undef DS_A_Q
#undef DS_B
#undef MM16
#undef BAR
#undef LGK
#undef VMC

  // ---- epilogue: per-row argmin over this block's 256 cols ----
  __syncthreads();  // all loads drained (vmcnt 0 at exit); LDS reused below
  float* cvs = (float*)&lds[0][0][0][0];  // [4][256]
  int* cis = (int*)(cvs + 4 * 256);       // [4][256]

  float bv[2][4][4];
  int bi[2][4][4];
#pragma unroll
  for (int qm = 0; qm < 2; ++qm)
#pragma unroll
    for (int m = 0; m < 4; ++m)
#pragma unroll
      for (int q = 0; q < 4; ++q) {
        bv[qm][m][q] = INFINITY;
        bi[qm][m][q] = 0;
      }
#pragma unroll
  for (int qn = 0; qn < 2; ++qn)  // ascending col order -> first-min ties
#pragma unroll
    for (int n = 0; n < 2; ++n) {
      const int col = c0g + wn * 64 + qn * 32 + n * 16 + l15;
      const float en = enorm[col];
#pragma unroll
      for (int qm = 0; qm < 2; ++qm)
#pragma unroll
        for (int m = 0; m < 4; ++m)
#pragma unroll
          for (int q = 0; q < 4; ++q) {
            const float s = en - acc[qm][m][qn][n][q];
            if (s < bv[qm][m][q]) {
              bv[qm][m][q] = s;
              bi[qm][m][q] = col;
            }
          }
    }
#pragma unroll
  for (int msk = 1; msk < 16; msk <<= 1) {
#pragma unroll
    for (int qm = 0; qm < 2; ++qm)
#pragma unroll
      for (int m = 0; m < 4; ++m)
#pragma unroll
        for (int q = 0; q < 4; ++q) {
          const float ov = __shfl_xor(bv[qm][m][q], msk);
          const int oi = __shfl_xor(bi[qm][m][q], msk);
          if (ov < bv[qm][m][q] || (ov == bv[qm][m][q] && oi < bi[qm][m][q])) {
            bv[qm][m][q] = ov;
            bi[qm][m][q] = oi;
          }
        }
  }
  if (l15 == 0) {
#pragma unroll
    for (int qm = 0; qm < 2; ++qm)
#pragma unroll
      for (int m = 0; m < 4; ++m)
#pragma unroll
        for (int q = 0; q < 4; ++q) {
          const int row = wm * 128 + qm * 64 + m * 16 + l4 * 4 + q;
          cvs[wn * 256 + row] = bv[qm][m][q];
          cis[wn * 256 + row] = bi[qm][m][q];
        }
  }
  __syncthreads();
  if (tid < 256) {
    float v = cvs[tid];
    int bidx = cis[tid];
#pragma unroll
    for (int q = 1; q < 4; ++q) {  // ascending wn -> ascending cols
      const float ov = cvs[q * 256 + tid];
      const int oi = cis[q * 256 + tid];
      if (ov < v) {
        v = ov;
        bidx = oi;
      }
    }
    cand_v[(size_t)by * NBT + bt0 + tid] = v;
    cand_i[(size_t)by * NBT + bt0 + tid] = bidx;
  }
}

// -------- combine + exact fp32 top-2 rescore + loss partial (s_best) -------
__global__ __launch_bounds__(256) void combine_rescore_kernel(
    const float* __restrict__ cand_v, const int* __restrict__ cand_i,
    const float* __restrict__ x, const float* __restrict__ emb,
    const float* __restrict__ enorm, int* __restrict__ idx_ws,
    float* __restrict__ idxf, float* __restrict__ lpart) {
  const int r = blockIdx.x * 256 + threadIdx.x;
  float v1 = INFINITY, v2 = INFINITY;
  int i1 = 0, i2 = 0;
#pragma unroll
  for (int nt = 0; nt < CT; ++nt) {  // ascending nt -> ascending index
    const float v = cand_v[(size_t)nt * NBT + r];
    const int i = cand_i[(size_t)nt * NBT + r];
    if (v < v1) {
      v2 = v1;
      i2 = i1;
      v1 = v;
      i1 = i;
    } else if (v < v2) {
      v2 = v;
      i2 = i;
    }
  }
  const int b = r >> 12, t = r & (NT - 1);
  const float* xb = x + (size_t)b * ND * NT + t;
  const float* e1 = emb + (size_t)i1 * ND;
  const float* e2 = emb + (size_t)i2 * ND;
  float d1 = 0.f, d2 = 0.f;
#pragma unroll 8
  for (int d = 0; d < ND; ++d) {
    const float xv = xb[(size_t)d * NT];
    d1 += xv * e1[d];
    d2 += xv * e2[d];
  }
  const float s1 = enorm[i1] - 2.f * d1;
  const float s2 = enorm[i2] - 2.f * d2;
  const bool take2 = (s2 < s1 || (s2 == s1 && i2 < i1));
  const int best = take2 ? i2 : i1;
  idx_ws[r] = best;
  idxf[r] = (float)best;
  // per-row loss term: sum_d (x-v)^2 - sum_d x^2 = enorm[best] - 2*dot_best
  float lsum = take2 ? s2 : s1;
#pragma unroll
  for (int m = 32; m; m >>= 1) lsum += __shfl_xor(lsum, m);
  __shared__ float wsum[4];
  if ((threadIdx.x & 63) == 0) wsum[threadIdx.x >> 6] = lsum;
  __syncthreads();
  if (threadIdx.x == 0)
    lpart[blockIdx.x] = wsum[0] + wsum[1] + wsum[2] + wsum[3];
}

// ----------------------------------------------- gather (emb -> [B,D,T]) ---
__global__ __launch_bounds__(256) void gather_kernel(
    const float* __restrict__ emb, const int* __restrict__ idx_ws,
    float* __restrict__ vals_out) {
  __shared__ float tile[64][65];
  const int tid = threadIdx.x;
  const int bt0 = blockIdx.x * 64;
  const int d0 = blockIdx.y * 64;
  const int b = bt0 / NT;
  const int t0 = bt0 % NT;
  {
    const int dd4 = (tid & 15) * 4;
    const int ttb = tid >> 4;
#pragma unroll
    for (int p = 0; p < 4; ++p) {
      const int tt = ttb + p * 16;
      const int r = idx_ws[bt0 + tt];
      float4 v = *(const float4*)&emb[(size_t)r * ND + d0 + dd4];
      tile[tt][dd4 + 0] = v.x;
      tile[tt][dd4 + 1] = v.y;
      tile[tt][dd4 + 2] = v.z;
      tile[tt][dd4 + 3] = v.w;
    }
  }
  __syncthreads();
  {
    const int tt4 = (tid & 15) * 4;
    const int ddb = tid >> 4;
#pragma unroll
    for (int p = 0; p < 4; ++p) {
      const int dd = ddb + p * 16;
      float4 v;
      v.x = tile[tt4 + 0][dd];
      v.y = tile[tt4 + 1][dd];
      v.z = tile[tt4 + 2][dd];
      v.w = tile[tt4 + 3][dd];
      const size_t o = (size_t)b * ND * NT + (size_t)(d0 + dd) * NT + t0 + tt4;
      *(float4*)&vals_out[o] = v;
    }
  }
}

// ----------------------------------------------------------------- loss ----
__global__ void loss_kernel(const float* __restrict__ partials, int n,
                            float* __restrict__ out) {
  float s = 0.f;
  for (int i = threadIdx.x; i < n; i += 256) s += partials[i];
#pragma unroll
  for (int m = 32; m; m >>= 1) s += __shfl_xor(s, m);
  __shared__ float wsum[4];
  if ((threadIdx.x & 63) == 0) wsum[threadIdx.x >> 6] = s;
  __syncthreads();
  if (threadIdx.x == 0)
    out[0] = 2.0f * (wsum[0] + wsum[1] + wsum[2] + wsum[3]) /
             (float)((size_t)NB * ND * NT);
}

// --------------------------------------------------------------- launch ----
extern "C" void kernel_launch(void* const* d_in, const int* in_sizes, int n_in,
                              void* d_out, int out_size, void* d_ws,
                              size_t ws_size, hipStream_t stream) {
  const float* x = (const float*)d_in[0];
  const float* emb = (const float*)d_in[1];
  float* out = (float*)d_out;
  float* vals_out = out;                         // [B, D, T]
  float* idxf_out = out + (size_t)NB * ND * NT;  // [B, T] as float
  float* loss_out = idxf_out + NBT;              // scalar

  u16* xh = (u16*)d_ws;                            // NBT*ND
  u16* xl = xh + (size_t)NBT * ND;                 // NBT*ND
  u16* eh2 = xl + (size_t)NBT * ND;                // NK*ND
  u16* el2 = eh2 + (size_t)NK * ND;                // NK*ND
  float* enorm = (float*)(el2 + (size_t)NK * ND);  // NK
  float* cand_v = enorm + NK;                      // CT * NBT
  int* cand_i = (int*)(cand_v + (size_t)CT * NBT);
  int* idx_ws = cand_i + (size_t)CT * NBT;  // NBT
  float* partials = (float*)(idx_ws + NBT); // 2048 (x^2) + 64 (rescore)

  conv_e_kernel<<<NK / 4, 256, 0, stream>>>(emb, eh2, el2, enorm);
  conv_x_kernel<<<dim3(NBT / 64, ND / 64), 256, 0, stream>>>(x, xh, xl,
                                                             partials);
  argmin_gemm_kernel<<<1024, 512, 0, stream>>>(xh, xl, eh2, el2, enorm, cand_v,
                                               cand_i);
  combine_rescore_kernel<<<NBT / 256, 256, 0, stream>>>(
      cand_v, cand_i, x, emb, enorm, idx_ws, idxf_out, partials + 2048);
  gather_kernel<<<dim3(NBT / 64, ND / 64), 256, 0, stream>>>(emb, idx_ws,
                                                             vals_out);
  loss_kernel<<<1, 256, 0, stream>>>(partials, 2048 + 64, loss_out);
}

// Round 13
// 254.470 us; speedup vs baseline: 1.0915x; 1.0836x over previous
//
#include <hip/hip_runtime.h>
#include <cstddef>
#include <cstdint>

#define NB 4
#define ND 512
#define NT 4096
#define NK 4096
#define NBT (NB * NT)
#define BKR 32         // real-k chunk
#define NCH (ND / BKR) // 16 chunks
#define CT (NK / 256)  // 16 candidate tiles

typedef __attribute__((ext_vector_type(4))) float f32x4;
typedef __attribute__((ext_vector_type(8))) short short8;
typedef __attribute__((ext_vector_type(8))) unsigned short u16x8;
typedef unsigned short u16;

__device__ inline u16 f2bf_rn(float f) {
  unsigned u = __float_as_uint(f);
  return (u16)((u + 0x7FFFu + ((u >> 16) & 1u)) >> 16);
}
__device__ inline float bf2f(u16 h) {
  return __uint_as_float(((unsigned)h) << 16);
}
__device__ inline void gload16(void* lds_p, const void* g) {
  __builtin_amdgcn_global_load_lds(
      (const __attribute__((address_space(1))) unsigned int*)g,
      (__attribute__((address_space(3))) unsigned int*)lds_p, 16, 0, 0);
}

// ---------------------------------------------------- e conversion + norm --
__global__ void conv_e_kernel(const float* __restrict__ emb,
                              u16* __restrict__ eh2, u16* __restrict__ el2,
                              float* __restrict__ enorm) {
  int row = blockIdx.x * 4 + (threadIdx.x >> 6);
  int l = threadIdx.x & 63;
  const float* e = emb + (size_t)row * ND;
  float s = 0.f;
#pragma unroll
  for (int i = 0; i < ND / 64; ++i) {
    int idx = l + i * 64;
    float v = e[idx];
    s += v * v;
    float v2 = 2.f * v;
    u16 h = f2bf_rn(v2);
    u16 lo = f2bf_rn(v2 - bf2f(h));
    eh2[(size_t)row * ND + idx] = h;
    el2[(size_t)row * ND + idx] = lo;
  }
#pragma unroll
  for (int m = 32; m; m >>= 1) s += __shfl_xor(s, m);
  if (l == 0) enorm[row] = s;
}

// ------------------- x conversion (+ transpose) + sum(x^2) partials --------
__global__ __launch_bounds__(256) void conv_x_kernel(const float* __restrict__ x,
                                                     u16* __restrict__ xh,
                                                     u16* __restrict__ xl,
                                                     float* __restrict__ xsq) {
  __shared__ float tile[64][68];
  const int tid = threadIdx.x;
  const int bt0 = blockIdx.x * 64, d0 = blockIdx.y * 64;
  const int b = bt0 / NT, t0 = bt0 % NT;
  const float* xb = x + (size_t)b * ND * NT;
  float s2 = 0.f;
  {
    const int tt4 = (tid & 15) * 4, ddb = tid >> 4;
#pragma unroll
    for (int p = 0; p < 4; ++p) {
      const int dd = ddb + p * 16;
      float4 v = *(const float4*)&xb[(size_t)(d0 + dd) * NT + t0 + tt4];
      s2 += v.x * v.x + v.y * v.y + v.z * v.z + v.w * v.w;
      *(float4*)&tile[dd][tt4] = v;
    }
  }
  __syncthreads();
  {
    const int t_loc = tid >> 2, dg = tid & 3;
    u16 hs[16], ls[16];
#pragma unroll
    for (int j = 0; j < 16; ++j) {
      float f = tile[dg * 16 + j][t_loc];
      u16 h = f2bf_rn(f);
      hs[j] = h;
      ls[j] = f2bf_rn(f - bf2f(h));
    }
    const size_t base = (size_t)(bt0 + t_loc) * ND + d0 + dg * 16;
    *(u16x8*)&xh[base] = *(const u16x8*)&hs[0];
    *(u16x8*)&xh[base + 8] = *(const u16x8*)&hs[8];
    *(u16x8*)&xl[base] = *(const u16x8*)&ls[0];
    *(u16x8*)&xl[base + 8] = *(const u16x8*)&ls[8];
  }
#pragma unroll
  for (int m = 32; m; m >>= 1) s2 += __shfl_xor(s2, m);
  __shared__ float wsum[4];
  if ((tid & 63) == 0) wsum[tid >> 6] = s2;
  __syncthreads();
  if (tid == 0)
    xsq[blockIdx.y * gridDim.x + blockIdx.x] =
        wsum[0] + wsum[1] + wsum[2] + wsum[3];
}

// ------------------------------- 16-wave 2-phase GEMM + argmin -------------
// 256x256 tile, 16 waves (4M x 4N), 64x64 output per wave (acc = 64 VGPR)
// -> 4 waves/SIMD (vs 2 before): the SIMD interleaves one wave's ds_reads
// with another's MFMAs inside the single-barrier chunk. Loop = minimum
// 2-phase T3 recipe: stage(t+1); reads(t); MFMA; __syncthreads() (implicit
// vmcnt(0)+lgkmcnt(0) drain is ~free after the MFMA burst, and is the
// provably-safe cross-wave stage/read sync: drain-before-barrier).
// Quad-operand BKR=32 residency (1.5x less traffic, r8-proven datapath).
__device__ __forceinline__ void stage_op(
    u16 (&lds)[2][4][256][BKR], int bn, int op, int tn,
    const u16* __restrict__ src, int rowbase, int w, int l) {
  if (tn >= NCH) return;
  const int kA = tn * BKR;
  const int rowL = w * 16 + (l >> 2);  // 16 waves x 16 rows = 256 rows
  const int gslot = (l & 3) ^ ((rowL >> 1) & 3);  // pre-swizzled source
  gload16(&lds[bn][op][w * 16][0],
          &src[(size_t)(rowbase + rowL) * ND + kA + gslot * 8]);
}

__global__ __launch_bounds__(1024, 4) void argmin_gemm_kernel(
    const u16* __restrict__ xh, const u16* __restrict__ xl,
    const u16* __restrict__ eh2, const u16* __restrict__ el2,
    const float* __restrict__ enorm, float* __restrict__ cand_v,
    int* __restrict__ cand_i) {
  __shared__ u16 lds[2][4][256][BKR];  // [buf][aH,aL,bH,bL][row][k] = 128 KiB
  const int tid = threadIdx.x;
  const int w = tid >> 6, l = tid & 63;
  const int l15 = l & 15, l4 = l >> 4;
  const int wm = w >> 2, wn = w & 3;  // 4x4 wave grid, 64x64 each
  // XCD-aware bijective swizzle: nwg=1024, 128 blocks per XCD chunk.
  const int id = blockIdx.x;
  const int id_sw = (id & 7) * 128 + (id >> 3);
  const int bx = id_sw & 63, by = id_sw >> 6;
  const int bt0 = bx * 256, c0g = by * 256;

  f32x4 acc[4][2][2];  // [m][qn][n] = 16 x f32x4 = 64 VGPR
#pragma unroll
  for (int m = 0; m < 4; ++m)
#pragma unroll
    for (int qn = 0; qn < 2; ++qn)
#pragma unroll
      for (int n = 0; n < 2; ++n) acc[m][qn][n] = (f32x4)0.f;

#define SLOT(row) (((l4) ^ (((row) >> 1) & 3)) * 8)
#define DS_A(AF, OP)                                                     \
  _Pragma("unroll") for (int m = 0; m < 4; ++m) {                        \
    const int row = wm * 64 + m * 16 + l15;                              \
    AF[m] = *(const short8*)&lds[cur][OP][row][SLOT(row)];               \
  }
#define DS_B(BF, OP)                                                     \
  _Pragma("unroll") for (int qn = 0; qn < 2; ++qn) {                     \
    _Pragma("unroll") for (int n = 0; n < 2; ++n) {                      \
      const int row = wn * 64 + qn * 32 + n * 16 + l15;                  \
      BF[qn * 2 + n] = *(const short8*)&lds[cur][OP][row][SLOT(row)];    \
    }                                                                    \
  }
#define MM(AF, BF)                                                       \
  _Pragma("unroll") for (int m = 0; m < 4; ++m) {                        \
    _Pragma("unroll") for (int qn = 0; qn < 2; ++qn) {                   \
      _Pragma("unroll") for (int n = 0; n < 2; ++n) {                    \
        acc[m][qn][n] = __builtin_amdgcn_mfma_f32_16x16x32_bf16(         \
            AF[m], BF[qn * 2 + n], acc[m][qn][n], 0, 0, 0);              \
      }                                                                  \
    }                                                                    \
  }

  // prologue: stage chunk 0; syncthreads drains (vmcnt 0) + barrier.
  stage_op(lds, 0, 0, 0, xh, bt0, w, l);   // aH
  stage_op(lds, 0, 2, 0, eh2, c0g, w, l);  // bH
  stage_op(lds, 0, 3, 0, el2, c0g, w, l);  // bL
  stage_op(lds, 0, 1, 0, xl, bt0, w, l);   // aL
  __syncthreads();

  for (int t = 0; t < NCH; ++t) {
    const int cur = t & 1;
    const int nb = cur ^ 1;
    const int tn = t + 1;
    // stage chunk t+1 early: in flight across the whole MFMA burst
    stage_op(lds, nb, 0, tn, xh, bt0, w, l);
    stage_op(lds, nb, 2, tn, eh2, c0g, w, l);
    stage_op(lds, nb, 3, tn, el2, c0g, w, l);
    stage_op(lds, nb, 1, tn, xl, bt0, w, l);
    // reads of chunk t (cur): safe — all waves drained before last barrier
    short8 bH[4], bL[4];
    DS_B(bH, 2);
    DS_B(bL, 3);
    {
      short8 aH[4];
      DS_A(aH, 0);
      MM(aH, bH);
      MM(aH, bL);
    }
    {
      short8 aL[4];
      DS_A(aL, 1);
      MM(aL, bH);
    }
    // implicit s_waitcnt vmcnt(0) lgkmcnt(0) + s_barrier:
    // drains THIS wave's chunk-(t+1) stages before the swap barrier
    // (cross-wave-correct), cost hidden behind the 48-MFMA burst.
    __syncthreads();
  }
#undef SLOT
#undef DS_A
#undef DS_B
#undef MM

  // ---- epilogue: per-row argmin over this block's 256 cols ----
  float* cvs = (float*)&lds[0][0][0][0];  // [4][256]
  int* cis = (int*)(cvs + 4 * 256);       // [4][256]

  float bv[4][4];
  int bi[4][4];
#pragma unroll
  for (int m = 0; m < 4; ++m)
#pragma unroll
    for (int q = 0; q < 4; ++q) {
      bv[m][q] = INFINITY;
      bi[m][q] = 0;
    }
#pragma unroll
  for (int qn = 0; qn < 2; ++qn)  // ascending col order -> first-min ties
#pragma unroll
    for (int n = 0; n < 2; ++n) {
      const int col = c0g + wn * 64 + qn * 32 + n * 16 + l15;
      const float en = enorm[col];
#pragma unroll
      for (int m = 0; m < 4; ++m)
#pragma unroll
        for (int q = 0; q < 4; ++q) {
          const float s = en - acc[m][qn][n][q];
          if (s < bv[m][q]) {
            bv[m][q] = s;
            bi[m][q] = col;
          }
        }
    }
#pragma unroll
  for (int msk = 1; msk < 16; msk <<= 1) {
#pragma unroll
    for (int m = 0; m < 4; ++m)
#pragma unroll
      for (int q = 0; q < 4; ++q) {
        const float ov = __shfl_xor(bv[m][q], msk);
        const int oi = __shfl_xor(bi[m][q], msk);
        if (ov < bv[m][q] || (ov == bv[m][q] && oi < bi[m][q])) {
          bv[m][q] = ov;
          bi[m][q] = oi;
        }
      }
  }
  if (l15 == 0) {
#pragma unroll
    for (int m = 0; m < 4; ++m)
#pragma unroll
      for (int q = 0; q < 4; ++q) {
        const int row = wm * 64 + m * 16 + l4 * 4 + q;
        cvs[wn * 256 + row] = bv[m][q];
        cis[wn * 256 + row] = bi[m][q];
      }
  }
  __syncthreads();
  if (tid < 256) {
    float v = cvs[tid];
    int bidx = cis[tid];
#pragma unroll
    for (int q = 1; q < 4; ++q) {  // ascending wn -> ascending cols
      const float ov = cvs[q * 256 + tid];
      const int oi = cis[q * 256 + tid];
      if (ov < v) {
        v = ov;
        bidx = oi;
      }
    }
    cand_v[(size_t)by * NBT + bt0 + tid] = v;
    cand_i[(size_t)by * NBT + bt0 + tid] = bidx;
  }
}

// -------- combine + exact fp32 top-2 rescore + loss partial (s_best) -------
__global__ __launch_bounds__(256) void combine_rescore_kernel(
    const float* __restrict__ cand_v, const int* __restrict__ cand_i,
    const float* __restrict__ x, const float* __restrict__ emb,
    const float* __restrict__ enorm, int* __restrict__ idx_ws,
    float* __restrict__ idxf, float* __restrict__ lpart) {
  const int r = blockIdx.x * 256 + threadIdx.x;
  float v1 = INFINITY, v2 = INFINITY;
  int i1 = 0, i2 = 0;
#pragma unroll
  for (int nt = 0; nt < CT; ++nt) {  // ascending nt -> ascending index
    const float v = cand_v[(size_t)nt * NBT + r];
    const int i = cand_i[(size_t)nt * NBT + r];
    if (v < v1) {
      v2 = v1;
      i2 = i1;
      v1 = v;
      i1 = i;
    } else if (v < v2) {
      v2 = v;
      i2 = i;
    }
  }
  const int b = r >> 12, t = r & (NT - 1);
  const float* xb = x + (size_t)b * ND * NT + t;
  const float* e1 = emb + (size_t)i1 * ND;
  const float* e2 = emb + (size_t)i2 * ND;
  float d1 = 0.f, d2 = 0.f;
#pragma unroll 8
  for (int d = 0; d < ND; ++d) {
    const float xv = xb[(size_t)d * NT];
    d1 += xv * e1[d];
    d2 += xv * e2[d];
  }
  const float s1 = enorm[i1] - 2.f * d1;
  const float s2 = enorm[i2] - 2.f * d2;
  const bool take2 = (s2 < s1 || (s2 == s1 && i2 < i1));
  const int best = take2 ? i2 : i1;
  idx_ws[r] = best;
  idxf[r] = (float)best;
  // per-row loss term: sum_d (x-v)^2 - sum_d x^2 = enorm[best] - 2*dot_best
  float lsum = take2 ? s2 : s1;
#pragma unroll
  for (int m = 32; m; m >>= 1) lsum += __shfl_xor(lsum, m);
  __shared__ float wsum[4];
  if ((threadIdx.x & 63) == 0) wsum[threadIdx.x >> 6] = lsum;
  __syncthreads();
  if (threadIdx.x == 0)
    lpart[blockIdx.x] = wsum[0] + wsum[1] + wsum[2] + wsum[3];
}

// ----------------------------------------------- gather (emb -> [B,D,T]) ---
__global__ __launch_bounds__(256) void gather_kernel(
    const float* __restrict__ emb, const int* __restrict__ idx_ws,
    float* __restrict__ vals_out) {
  __shared__ float tile[64][65];
  const int tid = threadIdx.x;
  const int bt0 = blockIdx.x * 64;
  const int d0 = blockIdx.y * 64;
  const int b = bt0 / NT;
  const int t0 = bt0 % NT;
  {
    const int dd4 = (tid & 15) * 4;
    const int ttb = tid >> 4;
#pragma unroll
    for (int p = 0; p < 4; ++p) {
      const int tt = ttb + p * 16;
      const int r = idx_ws[bt0 + tt];
      float4 v = *(const float4*)&emb[(size_t)r * ND + d0 + dd4];
      tile[tt][dd4 + 0] = v.x;
      tile[tt][dd4 + 1] = v.y;
      tile[tt][dd4 + 2] = v.z;
      tile[tt][dd4 + 3] = v.w;
    }
  }
  __syncthreads();
  {
    const int tt4 = (tid & 15) * 4;
    const int ddb = tid >> 4;
#pragma unroll
    for (int p = 0; p < 4; ++p) {
      const int dd = ddb + p * 16;
      float4 v;
      v.x = tile[tt4 + 0][dd];
      v.y = tile[tt4 + 1][dd];
      v.z = tile[tt4 + 2][dd];
      v.w = tile[tt4 + 3][dd];
      const size_t o = (size_t)b * ND * NT + (size_t)(d0 + dd) * NT + t0 + tt4;
      *(float4*)&vals_out[o] = v;
    }
  }
}

// ----------------------------------------------------------------- loss ----
__global__ void loss_kernel(const float* __restrict__ partials, int n,
                            float* __restrict__ out) {
  float s = 0.f;
  for (int i = threadIdx.x; i < n; i += 256) s += partials[i];
#pragma unroll
  for (int m = 32; m; m >>= 1) s += __shfl_xor(s, m);
  __shared__ float wsum[4];
  if ((threadIdx.x & 63) == 0) wsum[threadIdx.x >> 6] = s;
  __syncthreads();
  if (threadIdx.x == 0)
    out[0] = 2.0f * (wsum[0] + wsum[1] + wsum[2] + wsum[3]) /
             (float)((size_t)NB * ND * NT);
}

// --------------------------------------------------------------- launch ----
extern "C" void kernel_launch(void* const* d_in, const int* in_sizes, int n_in,
                              void* d_out, int out_size, void* d_ws,
                              size_t ws_size, hipStream_t stream) {
  const float* x = (const float*)d_in[0];
  const float* emb = (const float*)d_in[1];
  float* out = (float*)d_out;
  float* vals_out = out;                         // [B, D, T]
  float* idxf_out = out + (size_t)NB * ND * NT;  // [B, T] as float
  float* loss_out = idxf_out + NBT;              // scalar

  u16* xh = (u16*)d_ws;                            // NBT*ND
  u16* xl = xh + (size_t)NBT * ND;                 // NBT*ND
  u16* eh2 = xl + (size_t)NBT * ND;                // NK*ND
  u16* el2 = eh2 + (size_t)NK * ND;                // NK*ND
  float* enorm = (float*)(el2 + (size_t)NK * ND);  // NK
  float* cand_v = enorm + NK;                      // CT * NBT
  int* cand_i = (int*)(cand_v + (size_t)CT * NBT);
  int* idx_ws = cand_i + (size_t)CT * NBT;  // NBT
  float* partials = (float*)(idx_ws + NBT); // 2048 (x^2) + 64 (rescore)

  conv_e_kernel<<<NK / 4, 256, 0, stream>>>(emb, eh2, el2, enorm);
  conv_x_kernel<<<dim3(NBT / 64, ND / 64), 256, 0, stream>>>(x, xh, xl,
                                                             partials);
  argmin_gemm_kernel<<<1024, 1024, 0, stream>>>(xh, xl, eh2, el2, enorm,
                                                cand_v, cand_i);
  combine_rescore_kernel<<<NBT / 256, 256, 0, stream>>>(
      cand_v, cand_i, x, emb, enorm, idx_ws, idxf_out, partials + 2048);
  gather_kernel<<<dim3(NBT / 64, ND / 64), 256, 0, stream>>>(emb, idx_ws,
                                                             vals_out);
  loss_kernel<<<1, 256, 0, stream>>>(partials, 2048 + 64, loss_out);
}

// Round 14
// 253.472 us; speedup vs baseline: 1.0958x; 1.0039x over previous
//
#include <hip/hip_runtime.h>
#include <cstddef>
#include <cstdint>

#define NB 4
#define ND 512
#define NT 4096
#define NK 4096
#define NBT (NB * NT)
#define BKR 32         // real-k chunk
#define NCH (ND / BKR) // 16 chunks
#define CT (NK / 256)  // 16 candidate tiles

typedef __attribute__((ext_vector_type(4))) float f32x4;
typedef __attribute__((ext_vector_type(8))) short short8;
typedef __attribute__((ext_vector_type(8))) unsigned short u16x8;
typedef unsigned short u16;

__device__ inline u16 f2bf_rn(float f) {
  unsigned u = __float_as_uint(f);
  return (u16)((u + 0x7FFFu + ((u >> 16) & 1u)) >> 16);
}
__device__ inline float bf2f(u16 h) {
  return __uint_as_float(((unsigned)h) << 16);
}
__device__ inline void gload16(void* lds_p, const void* g) {
  __builtin_amdgcn_global_load_lds(
      (const __attribute__((address_space(1))) unsigned int*)g,
      (__attribute__((address_space(3))) unsigned int*)lds_p, 16, 0, 0);
}

// ---------------------------------------------------- e conversion + norm --
__global__ void conv_e_kernel(const float* __restrict__ emb,
                              u16* __restrict__ eh2, u16* __restrict__ el2,
                              float* __restrict__ enorm) {
  int row = blockIdx.x * 4 + (threadIdx.x >> 6);
  int l = threadIdx.x & 63;
  const float* e = emb + (size_t)row * ND;
  float s = 0.f;
#pragma unroll
  for (int i = 0; i < ND / 64; ++i) {
    int idx = l + i * 64;
    float v = e[idx];
    s += v * v;
    float v2 = 2.f * v;
    u16 h = f2bf_rn(v2);
    u16 lo = f2bf_rn(v2 - bf2f(h));
    eh2[(size_t)row * ND + idx] = h;
    el2[(size_t)row * ND + idx] = lo;
  }
#pragma unroll
  for (int m = 32; m; m >>= 1) s += __shfl_xor(s, m);
  if (l == 0) enorm[row] = s;
}

// ------------------- x conversion (+ transpose) + sum(x^2) partials --------
__global__ __launch_bounds__(256) void conv_x_kernel(const float* __restrict__ x,
                                                     u16* __restrict__ xh,
                                                     u16* __restrict__ xl,
                                                     float* __restrict__ xsq) {
  __shared__ float tile[64][68];
  const int tid = threadIdx.x;
  const int bt0 = blockIdx.x * 64, d0 = blockIdx.y * 64;
  const int b = bt0 / NT, t0 = bt0 % NT;
  const float* xb = x + (size_t)b * ND * NT;
  float s2 = 0.f;
  {
    const int tt4 = (tid & 15) * 4, ddb = tid >> 4;
#pragma unroll
    for (int p = 0; p < 4; ++p) {
      const int dd = ddb + p * 16;
      float4 v = *(const float4*)&xb[(size_t)(d0 + dd) * NT + t0 + tt4];
      s2 += v.x * v.x + v.y * v.y + v.z * v.z + v.w * v.w;
      *(float4*)&tile[dd][tt4] = v;
    }
  }
  __syncthreads();
  {
    const int t_loc = tid >> 2, dg = tid & 3;
    u16 hs[16], ls[16];
#pragma unroll
    for (int j = 0; j < 16; ++j) {
      float f = tile[dg * 16 + j][t_loc];
      u16 h = f2bf_rn(f);
      hs[j] = h;
      ls[j] = f2bf_rn(f - bf2f(h));
    }
    const size_t base = (size_t)(bt0 + t_loc) * ND + d0 + dg * 16;
    *(u16x8*)&xh[base] = *(const u16x8*)&hs[0];
    *(u16x8*)&xh[base + 8] = *(const u16x8*)&hs[8];
    *(u16x8*)&xl[base] = *(const u16x8*)&ls[0];
    *(u16x8*)&xl[base + 8] = *(const u16x8*)&ls[8];
  }
#pragma unroll
  for (int m = 32; m; m >>= 1) s2 += __shfl_xor(s2, m);
  __shared__ float wsum[4];
  if ((tid & 63) == 0) wsum[tid >> 6] = s2;
  __syncthreads();
  if (tid == 0)
    xsq[blockIdx.y * gridDim.x + blockIdx.x] =
        wsum[0] + wsum[1] + wsum[2] + wsum[3];
}

// ------------------- 16-wave segment-pipelined GEMM + argmin ---------------
// r13 (256x256, 16 waves of 64x64, quad-op BKR=32, 1 barrier/chunk) with the
// chunk body SEGMENT-PIPELINED: first product's 8 reads up front, later
// operand reads issued UNDER the preceding MFMA burst (in-order lgkmcnt ->
// compiler emits counted waits). Serialized read-prefix per chunk drops from
// 16 reads (3072 cyc/CU) to 8 (1536); bL lands under MM1, aL under other
// waves' MM tails. Register profile identical to r13 (peak 3 operand arrays
// live = 48 VGPR beside 64-reg acc; the 4-array order would spill - r9).
__device__ __forceinline__ void stage_op(
    u16 (&lds)[2][4][256][BKR], int bn, int op, int tn,
    const u16* __restrict__ src, int rowbase, int w, int l) {
  if (tn >= NCH) return;
  const int kA = tn * BKR;
  const int rowL = w * 16 + (l >> 2);  // 16 waves x 16 rows = 256 rows
  const int gslot = (l & 3) ^ ((rowL >> 1) & 3);  // pre-swizzled source
  gload16(&lds[bn][op][w * 16][0],
          &src[(size_t)(rowbase + rowL) * ND + kA + gslot * 8]);
}

__global__ __launch_bounds__(1024, 4) void argmin_gemm_kernel(
    const u16* __restrict__ xh, const u16* __restrict__ xl,
    const u16* __restrict__ eh2, const u16* __restrict__ el2,
    const float* __restrict__ enorm, float* __restrict__ cand_v,
    int* __restrict__ cand_i) {
  __shared__ u16 lds[2][4][256][BKR];  // [buf][aH,aL,bH,bL][row][k] = 128 KiB
  const int tid = threadIdx.x;
  const int w = tid >> 6, l = tid & 63;
  const int l15 = l & 15, l4 = l >> 4;
  const int wm = w >> 2, wn = w & 3;  // 4x4 wave grid, 64x64 each
  // XCD-aware bijective swizzle: nwg=1024, 128 blocks per XCD chunk.
  const int id = blockIdx.x;
  const int id_sw = (id & 7) * 128 + (id >> 3);
  const int bx = id_sw & 63, by = id_sw >> 6;
  const int bt0 = bx * 256, c0g = by * 256;

  f32x4 acc[4][2][2];  // [m][qn][n] = 16 x f32x4 = 64 VGPR
#pragma unroll
  for (int m = 0; m < 4; ++m)
#pragma unroll
    for (int qn = 0; qn < 2; ++qn)
#pragma unroll
      for (int n = 0; n < 2; ++n) acc[m][qn][n] = (f32x4)0.f;

#define SLOT(row) (((l4) ^ (((row) >> 1) & 3)) * 8)
#define DS_A(AF, OP)                                                     \
  _Pragma("unroll") for (int m = 0; m < 4; ++m) {                        \
    const int row = wm * 64 + m * 16 + l15;                              \
    AF[m] = *(const short8*)&lds[cur][OP][row][SLOT(row)];               \
  }
#define DS_B(BF, OP)                                                     \
  _Pragma("unroll") for (int qn = 0; qn < 2; ++qn) {                     \
    _Pragma("unroll") for (int n = 0; n < 2; ++n) {                      \
      const int row = wn * 64 + qn * 32 + n * 16 + l15;                  \
      BF[qn * 2 + n] = *(const short8*)&lds[cur][OP][row][SLOT(row)];    \
    }                                                                    \
  }
#define MM(AF, BF)                                                       \
  _Pragma("unroll") for (int m = 0; m < 4; ++m) {                        \
    _Pragma("unroll") for (int qn = 0; qn < 2; ++qn) {                   \
      _Pragma("unroll") for (int n = 0; n < 2; ++n) {                    \
        acc[m][qn][n] = __builtin_amdgcn_mfma_f32_16x16x32_bf16(         \
            AF[m], BF[qn * 2 + n], acc[m][qn][n], 0, 0, 0);              \
      }                                                                  \
    }                                                                    \
  }
#define SB0 __builtin_amdgcn_sched_barrier(0)

  // prologue: stage chunk 0; syncthreads drains (vmcnt 0) + barrier.
  stage_op(lds, 0, 0, 0, xh, bt0, w, l);   // aH
  stage_op(lds, 0, 2, 0, eh2, c0g, w, l);  // bH
  stage_op(lds, 0, 3, 0, el2, c0g, w, l);  // bL
  stage_op(lds, 0, 1, 0, xl, bt0, w, l);   // aL
  __syncthreads();

  for (int t = 0; t < NCH; ++t) {
    const int cur = t & 1;
    const int nb = cur ^ 1;
    const int tn = t + 1;
    // stage chunk t+1 early: in flight across the whole chunk
    stage_op(lds, nb, 0, tn, xh, bt0, w, l);
    stage_op(lds, nb, 2, tn, eh2, c0g, w, l);
    stage_op(lds, nb, 3, tn, el2, c0g, w, l);
    stage_op(lds, nb, 1, tn, xl, bt0, w, l);
    // ---- S1: ONLY the first product's reads (8) ----
    short8 aH[4], bH[4];
    DS_A(aH, 0);
    DS_B(bH, 2);
    SB0;
    {
      // ---- S2: bL reads issue under MM1 (counted lgkmcnt) ----
      short8 bL[4];
      DS_B(bL, 3);
      MM(aH, bH);
      SB0;
      // ---- S3: MM2; aH,bL die at end ----
      MM(aH, bL);
      SB0;
    }
    {
      // ---- S4: aL read (covered by other waves' MM tails) + MM3 ----
      short8 aL[4];
      DS_A(aL, 1);
      MM(aL, bH);
    }
    // implicit vmcnt(0)+lgkmcnt(0) drain + barrier: chunk t+1 staged loads
    // have had the whole chunk to land; cross-wave-correct swap sync.
    __syncthreads();
  }
#undef SLOT
#undef DS_A
#undef DS_B
#undef MM
#undef SB0

  // ---- epilogue: per-row argmin over this block's 256 cols ----
  float* cvs = (float*)&lds[0][0][0][0];  // [4][256]
  int* cis = (int*)(cvs + 4 * 256);       // [4][256]

  float bv[4][4];
  int bi[4][4];
#pragma unroll
  for (int m = 0; m < 4; ++m)
#pragma unroll
    for (int q = 0; q < 4; ++q) {
      bv[m][q] = INFINITY;
      bi[m][q] = 0;
    }
#pragma unroll
  for (int qn = 0; qn < 2; ++qn)  // ascending col order -> first-min ties
#pragma unroll
    for (int n = 0; n < 2; ++n) {
      const int col = c0g + wn * 64 + qn * 32 + n * 16 + l15;
      const float en = enorm[col];
#pragma unroll
      for (int m = 0; m < 4; ++m)
#pragma unroll
        for (int q = 0; q < 4; ++q) {
          const float s = en - acc[m][qn][n][q];
          if (s < bv[m][q]) {
            bv[m][q] = s;
            bi[m][q] = col;
          }
        }
    }
#pragma unroll
  for (int msk = 1; msk < 16; msk <<= 1) {
#pragma unroll
    for (int m = 0; m < 4; ++m)
#pragma unroll
      for (int q = 0; q < 4; ++q) {
        const float ov = __shfl_xor(bv[m][q], msk);
        const int oi = __shfl_xor(bi[m][q], msk);
        if (ov < bv[m][q] || (ov == bv[m][q] && oi < bi[m][q])) {
          bv[m][q] = ov;
          bi[m][q] = oi;
        }
      }
  }
  if (l15 == 0) {
#pragma unroll
    for (int m = 0; m < 4; ++m)
#pragma unroll
      for (int q = 0; q < 4; ++q) {
        const int row = wm * 64 + m * 16 + l4 * 4 + q;
        cvs[wn * 256 + row] = bv[m][q];
        cis[wn * 256 + row] = bi[m][q];
      }
  }
  __syncthreads();
  if (tid < 256) {
    float v = cvs[tid];
    int bidx = cis[tid];
#pragma unroll
    for (int q = 1; q < 4; ++q) {  // ascending wn -> ascending cols
      const float ov = cvs[q * 256 + tid];
      const int oi = cis[q * 256 + tid];
      if (ov < v) {
        v = ov;
        bidx = oi;
      }
    }
    cand_v[(size_t)by * NBT + bt0 + tid] = v;
    cand_i[(size_t)by * NBT + bt0 + tid] = bidx;
  }
}

// -------- combine + exact fp32 top-2 rescore + loss partial (s_best) -------
__global__ __launch_bounds__(256) void combine_rescore_kernel(
    const float* __restrict__ cand_v, const int* __restrict__ cand_i,
    const float* __restrict__ x, const float* __restrict__ emb,
    const float* __restrict__ enorm, int* __restrict__ idx_ws,
    float* __restrict__ idxf, float* __restrict__ lpart) {
  const int r = blockIdx.x * 256 + threadIdx.x;
  float v1 = INFINITY, v2 = INFINITY;
  int i1 = 0, i2 = 0;
#pragma unroll
  for (int nt = 0; nt < CT; ++nt) {  // ascending nt -> ascending index
    const float v = cand_v[(size_t)nt * NBT + r];
    const int i = cand_i[(size_t)nt * NBT + r];
    if (v < v1) {
      v2 = v1;
      i2 = i1;
      v1 = v;
      i1 = i;
    } else if (v < v2) {
      v2 = v;
      i2 = i;
    }
  }
  const int b = r >> 12, t = r & (NT - 1);
  const float* xb = x + (size_t)b * ND * NT + t;
  const float* e1 = emb + (size_t)i1 * ND;
  const float* e2 = emb + (size_t)i2 * ND;
  float d1 = 0.f, d2 = 0.f;
#pragma unroll 8
  for (int d = 0; d < ND; ++d) {
    const float xv = xb[(size_t)d * NT];
    d1 += xv * e1[d];
    d2 += xv * e2[d];
  }
  const float s1 = enorm[i1] - 2.f * d1;
  const float s2 = enorm[i2] - 2.f * d2;
  const bool take2 = (s2 < s1 || (s2 == s1 && i2 < i1));
  const int best = take2 ? i2 : i1;
  idx_ws[r] = best;
  idxf[r] = (float)best;
  // per-row loss term: sum_d (x-v)^2 - sum_d x^2 = enorm[best] - 2*dot_best
  float lsum = take2 ? s2 : s1;
#pragma unroll
  for (int m = 32; m; m >>= 1) lsum += __shfl_xor(lsum, m);
  __shared__ float wsum[4];
  if ((threadIdx.x & 63) == 0) wsum[threadIdx.x >> 6] = lsum;
  __syncthreads();
  if (threadIdx.x == 0)
    lpart[blockIdx.x] = wsum[0] + wsum[1] + wsum[2] + wsum[3];
}

// ----------------------------------------------- gather (emb -> [B,D,T]) ---
__global__ __launch_bounds__(256) void gather_kernel(
    const float* __restrict__ emb, const int* __restrict__ idx_ws,
    float* __restrict__ vals_out) {
  __shared__ float tile[64][65];
  const int tid = threadIdx.x;
  const int bt0 = blockIdx.x * 64;
  const int d0 = blockIdx.y * 64;
  const int b = bt0 / NT;
  const int t0 = bt0 % NT;
  {
    const int dd4 = (tid & 15) * 4;
    const int ttb = tid >> 4;
#pragma unroll
    for (int p = 0; p < 4; ++p) {
      const int tt = ttb + p * 16;
      const int r = idx_ws[bt0 + tt];
      float4 v = *(const float4*)&emb[(size_t)r * ND + d0 + dd4];
      tile[tt][dd4 + 0] = v.x;
      tile[tt][dd4 + 1] = v.y;
      tile[tt][dd4 + 2] = v.z;
      tile[tt][dd4 + 3] = v.w;
    }
  }
  __syncthreads();
  {
    const int tt4 = (tid & 15) * 4;
    const int ddb = tid >> 4;
#pragma unroll
    for (int p = 0; p < 4; ++p) {
      const int dd = ddb + p * 16;
      float4 v;
      v.x = tile[tt4 + 0][dd];
      v.y = tile[tt4 + 1][dd];
      v.z = tile[tt4 + 2][dd];
      v.w = tile[tt4 + 3][dd];
      const size_t o = (size_t)b * ND * NT + (size_t)(d0 + dd) * NT + t0 + tt4;
      *(float4*)&vals_out[o] = v;
    }
  }
}

// ----------------------------------------------------------------- loss ----
__global__ void loss_kernel(const float* __restrict__ partials, int n,
                            float* __restrict__ out) {
  float s = 0.f;
  for (int i = threadIdx.x; i < n; i += 256) s += partials[i];
#pragma unroll
  for (int m = 32; m; m >>= 1) s += __shfl_xor(s, m);
  __shared__ float wsum[4];
  if ((threadIdx.x & 63) == 0) wsum[threadIdx.x >> 6] = s;
  __syncthreads();
  if (threadIdx.x == 0)
    out[0] = 2.0f * (wsum[0] + wsum[1] + wsum[2] + wsum[3]) /
             (float)((size_t)NB * ND * NT);
}

// --------------------------------------------------------------- launch ----
extern "C" void kernel_launch(void* const* d_in, const int* in_sizes, int n_in,
                              void* d_out, int out_size, void* d_ws,
                              size_t ws_size, hipStream_t stream) {
  const float* x = (const float*)d_in[0];
  const float* emb = (const float*)d_in[1];
  float* out = (float*)d_out;
  float* vals_out = out;                         // [B, D, T]
  float* idxf_out = out + (size_t)NB * ND * NT;  // [B, T] as float
  float* loss_out = idxf_out + NBT;              // scalar

  u16* xh = (u16*)d_ws;                            // NBT*ND
  u16* xl = xh + (size_t)NBT * ND;                 // NBT*ND
  u16* eh2 = xl + (size_t)NBT * ND;                // NK*ND
  u16* el2 = eh2 + (size_t)NK * ND;                // NK*ND
  float* enorm = (float*)(el2 + (size_t)NK * ND);  // NK
  float* cand_v = enorm + NK;                      // CT * NBT
  int* cand_i = (int*)(cand_v + (size_t)CT * NBT);
  int* idx_ws = cand_i + (size_t)CT * NBT;  // NBT
  float* partials = (float*)(idx_ws + NBT); // 2048 (x^2) + 64 (rescore)

  conv_e_kernel<<<NK / 4, 256, 0, stream>>>(emb, eh2, el2, enorm);
  conv_x_kernel<<<dim3(NBT / 64, ND / 64), 256, 0, stream>>>(x, xh, xl,
                                                             partials);
  argmin_gemm_kernel<<<1024, 1024, 0, stream>>>(xh, xl, eh2, el2, enorm,
                                                cand_v, cand_i);
  combine_rescore_kernel<<<NBT / 256, 256, 0, stream>>>(
      cand_v, cand_i, x, emb, enorm, idx_ws, idxf_out, partials + 2048);
  gather_kernel<<<dim3(NBT / 64, ND / 64), 256, 0, stream>>>(emb, idx_ws,
                                                             vals_out);
  loss_kernel<<<1, 256, 0, stream>>>(partials, 2048 + 64, loss_out);
}